// Round 9
// baseline (162.278 us; speedup 1.0000x reference)
//
#include <hip/hip_runtime.h>

// Fused grouped-QKV GEMM: out[t,kv,g,d] = sum_e in[t,e]*W[e,kv,g,d] + bias
// M=64, K=4096, N=6144. fp32 in/out.
//
// R16: deeper MLP. Ledger: schedule (R8/R9), traffic (R12), occupancy
// (R14), LDS demand (R15) all ~null; R13: latency-bound at low TLP; fills
// (~119us) unconditional. Effective W rate stuck at ~2.8TB/s while HBM
// supply is 6.8 -> the invariant across all rounds is IN-FLIGHT BYTES PER
// WAVE (Little's law), not waves. This round: W prefetch depth 2->4
// (8 dwordx4 in flight/wave, consumed 3 bodies after issue) and A depth
// 1->2 (8 in flight, consumed 2 bodies after issue) => ~2x in-flight.
// VGPR ~100 < 128 keeps 12 waves/CU. Everything else identical to R15
// (bf16-pair LDS, 2-way-bank swizzle, NT=192/KSPLIT=4/768 blocks=3 per CU,
// plain-store partials + XCD-aligned reduce).

#define N_COLS 6144
#define K_DIM  4096
#define Q_SZ   (64 * 4096)
#define K_OFF  Q_SZ
#define V_OFF  (Q_SZ + 64 * 1024)
#define OUT_ELEMS 393216   // 64*6144
#define NT     192         // n-tiles of 32
#define KSPLIT 4           // 1024 k per block -> 768 blocks (3/CU, exact)
#define BK     64
#define TILES  16          // 1024/64
#define NPR    32          // pair-rows per tile (BK/2)

typedef __bf16 bf16x2 __attribute__((ext_vector_type(2)));
typedef __bf16 bf16x8 __attribute__((ext_vector_type(8)));
typedef float  f32x4  __attribute__((ext_vector_type(4)));
typedef unsigned int u32x4 __attribute__((ext_vector_type(4)));

__device__ __forceinline__ int out_index(int t, int n) {
    const int kv = n / 768;
    const int g  = (n >> 7) % 6;
    const int d  = n & 127;
    if (g < 4)  return t * 4096 + kv * 512 + g * 128 + d;   // q
    if (g == 4) return K_OFF + t * 1024 + kv * 128 + d;     // k
    return V_OFF + t * 1024 + kv * 128 + d;                 // v
}

__device__ __forceinline__ unsigned pack_bf16(float lo, float hi) {
    bf16x2 p;
    p[0] = (__bf16)lo;     // k even -> low 16 bits (matches A-pack order)
    p[1] = (__bf16)hi;     // k odd  -> high 16 bits
    return __builtin_bit_cast(unsigned, p);
}

__global__ __launch_bounds__(256, 3)
void qkv_gemm(const float* __restrict__ in, const float* __restrict__ w,
              float* __restrict__ part) {
    // [pr][n] u32 grid: word (pr, n ^ ((pr>>2&1)<<4)) = bf16 pair of
    // W[k=2pr][n], W[k=2pr+1][n]. 2 x 4KB.
    __shared__ unsigned Ws[2][NPR * 32];

    const int tid  = threadIdx.x;
    const int nt   = blockIdx.x % NT;    // bid%8 = nt%8: k-split blocks of a
    const int kq   = blockIdx.x / NT;    // column share an XCD
    const int n0   = nt * 32;
    const int k0   = kq * (BK * TILES);  // kq*1024
    const int wid  = tid >> 6;
    const int lane = tid & 63;
    const int l15  = lane & 15;
    const int kblk = lane >> 4;

    // staging: thread owns pair-row pr = tid>>3 (0..31), chunk c = tid&7
    // (cols 4c..4c+3). Loads global rows k=2pr,2pr+1, packs 4 u32, one
    // swizzled ds_write_b128.
    const int pr = tid >> 3;
    const int c  = tid & 7;
    const int wcol = (c * 4) ^ (((pr >> 2) & 1) << 4);

    f32x4 acc[2];
    acc[0] = (f32x4){0.f, 0.f, 0.f, 0.f};
    acc[1] = (f32x4){0.f, 0.f, 0.f, 0.f};

    f32x4 wreg[4][2];          // 4 rotating sets (depth-4 W prefetch)
    float4 a[2][4];            // 2 rotating sets (depth-2 A prefetch)

    const float* wbase = w + ((size_t)k0 + pr * 2) * N_COLS + n0 + c * 4;
    const float* abase = in + (size_t)(wid * 16 + l15) * K_DIM + k0 + kblk * 8;

    // read-side swizzled cols (uniform per thread): (pr>>2)&1 == kblk&1
    // for all 4 pair-rows of a frag read.
    const int nbx0 = (0 * 16 + l15) ^ ((kblk & 1) << 4);
    const int nbx1 = (1 * 16 + l15) ^ ((kblk & 1) << 4);

    auto WLOAD = [&](int s, int set) {
        const float* p = wbase + (size_t)s * BK * N_COLS;
        wreg[set][0] = *(const f32x4*)p;             // k = 2pr
        wreg[set][1] = *(const f32x4*)(p + N_COLS);  // k = 2pr+1
    };
    auto DSWRITE = [&](int set, int buf) {
        u32x4 w4;
        #pragma unroll
        for (int i = 0; i < 4; ++i)
            w4[i] = pack_bf16(wreg[set][0][i], wreg[set][1][i]);
        *(u32x4*)&Ws[buf][pr * 32 + wcol] = w4;
    };
    auto ALOAD = [&](int s, int set) {
        const float* ap = abase + (size_t)s * BK;
        a[set][0] = *(const float4*)ap;           // half0: k 0..7 (kblk slice)
        a[set][1] = *(const float4*)(ap + 4);
        a[set][2] = *(const float4*)(ap + 32);    // half1: k 32..39
        a[set][3] = *(const float4*)(ap + 36);
    };

    // prologue: W tiles 0..3 and A tiles 0..1 in flight; commit tile0.
    WLOAD(0, 0);
    ALOAD(0, 0);
    WLOAD(1, 1);
    WLOAD(2, 2);
    WLOAD(3, 3);
    ALOAD(1, 1);
    DSWRITE(0, 0);             // auto vmcnt wait: only wreg[0]'s 2 loads
    asm volatile("s_waitcnt lgkmcnt(0)" ::: "memory");
    __builtin_amdgcn_s_barrier();

    #pragma unroll
    for (int s = 0; s < TILES; ++s) {
        // 1. pack A(s) from set s&1 (loads issued 2 bodies ago)
        bf16x8 av[2];
        #pragma unroll
        for (int h = 0; h < 2; ++h) {
            const float4 lo = a[s & 1][2 * h];
            const float4 hi = a[s & 1][2 * h + 1];
            av[h][0] = (__bf16)lo.x; av[h][1] = (__bf16)lo.y;
            av[h][2] = (__bf16)lo.z; av[h][3] = (__bf16)lo.w;
            av[h][4] = (__bf16)hi.x; av[h][5] = (__bf16)hi.y;
            av[h][6] = (__bf16)hi.z; av[h][7] = (__bf16)hi.w;
        }

        // 2. refill the just-freed sets (in flight across barriers)
        if (s + 4 < TILES) WLOAD(s + 4, s & 3);
        if (s + 2 < TILES) ALOAD(s + 2, s & 1);

        // 3. B-frags: 4 ds_read_b32 each, bit_cast to bf16x8. No cvts.
        #pragma unroll
        for (int h = 0; h < 2; ++h) {
            const int prb = h * 16 + kblk * 4;
            #pragma unroll
            for (int nfi = 0; nfi < 2; ++nfi) {
                const int nbx = nfi ? nbx1 : nbx0;
                u32x4 bu;
                #pragma unroll
                for (int i = 0; i < 4; ++i)
                    bu[i] = Ws[s & 1][(prb + i) * 32 + nbx];
                acc[nfi] = __builtin_amdgcn_mfma_f32_16x16x32_bf16(
                    av[h], __builtin_bit_cast(bf16x8, bu), acc[nfi], 0, 0, 0);
            }
        }

        // 4/5. commit tile s+1 (set loaded 3 bodies ago); one barrier/tile
        if (s + 1 < TILES) {
            DSWRITE((s + 1) & 3, (s + 1) & 1);  // waits only WLOAD(s+1)
            asm volatile("s_waitcnt lgkmcnt(0)" ::: "memory");
            __builtin_amdgcn_s_barrier();
        }
    }

    // partials: C/D col = l15 (n), row = kblk*4 + r; wave wid owns rows
    // wid*16..wid*16+15. Plain stores (keep L2-resident for the reducer).
    float* pb = part + (size_t)kq * OUT_ELEMS;
    #pragma unroll
    for (int nfi = 0; nfi < 2; ++nfi) {
        const int n = n0 + nfi * 16 + l15;
        #pragma unroll
        for (int r = 0; r < 4; ++r) {
            const int t = wid * 16 + kblk * 4 + r;
            pb[(size_t)t * N_COLS + n] = acc[nfi][r];
        }
    }
}

// sum KSPLIT partials + bias, scatter to q|k|v. Grid 384: nt = bid%192 so
// bid%8 = nt%8 -> same XCD as the gemm blocks that wrote column nt (L2
// hits on surviving partial lines). Block half h = bid/192 of column nt.
__global__ __launch_bounds__(256)
void qkv_reduce(const float* __restrict__ part, const float* __restrict__ bias,
                float* __restrict__ out) {
    const int nt = blockIdx.x % NT;
    const int h  = blockIdx.x / NT;
    const int t  = h * 32 + (threadIdx.x >> 3);
    const int n  = nt * 32 + (threadIdx.x & 7) * 4;
    const size_t i = (size_t)t * N_COLS + n;
    f32x4 s = *(const f32x4*)(bias + n);
    #pragma unroll
    for (int kq = 0; kq < KSPLIT; ++kq)
        s += *(const f32x4*)(part + (size_t)kq * OUT_ELEMS + i);
    *(f32x4*)(out + out_index(t, n)) = s;   // 4-chunk never crosses d-block
}

extern "C" void kernel_launch(void* const* d_in, const int* in_sizes, int n_in,
                              void* d_out, int out_size, void* d_ws, size_t ws_size,
                              hipStream_t stream) {
    const float* in   = (const float*)d_in[0];  // [64, 4096]
    const float* w    = (const float*)d_in[1];  // [4096, 8, 6, 128]
    const float* bias = (const float*)d_in[2];  // [8, 6, 128]
    float* out  = (float*)d_out;
    float* part = (float*)d_ws;                 // 4 * 1.57MB = 6.3MB fp32

    qkv_gemm<<<NT * KSPLIT, 256, 0, stream>>>(in, w, part);
    qkv_reduce<<<NT * 2, 256, 0, stream>>>(part, bias, out);
}